// Round 1
// baseline (502.964 us; speedup 1.0000x reference)
//
#include <hip/hip_runtime.h>

#define NN   256
#define CCH  128
#define HH   4
#define DD   32
#define HDIM 128
#define LN_EPS 1e-5f
#define QK_SCALE 0.17677669529663689f  // 1/sqrt(32)

typedef float f4 __attribute__((ext_vector_type(4)));

#define XS_STRIDE 132   // 64-row x tiles, pad to kill bank conflicts, 16B-aligned rows
#define KS        36    // attention LDS tiles stride (36*4B: 16B-aligned, <=4-way conflicts)

// ---------------- Kernel 1: LayerNorm + q/k/v/gate projections + pair bias ----------------
__global__ __launch_bounds__(256)
void k_proj(const float* __restrict__ act, const float* __restrict__ ln_g,
            const float* __restrict__ ln_b,
            const float* __restrict__ wq, const float* __restrict__ wk,
            const float* __restrict__ wv, const float* __restrict__ wg,
            const float* __restrict__ w2d, const float* __restrict__ bg,
            float* __restrict__ qo, float* __restrict__ ko,
            float* __restrict__ vo, float* __restrict__ go,
            float* __restrict__ b2d)
{
    __shared__ float xs[64 * XS_STRIDE];   // 33.8 KB  LN'd activations [64][128]
    __shared__ float ws[64 * 128];         // 32 KB    staged weight half-tile
    const int t = threadIdx.x;
    const long p0 = (long)blockIdx.x * 64;

    // load 64 positions x 128 channels, vectorized
    {
        const f4* af = (const f4*)(act + p0 * CCH);
        #pragma unroll
        for (int j = 0; j < 8; ++j) {
            int fidx = t + j * 256;
            int r = fidx >> 5, c4 = (fidx & 31) << 2;
            *(f4*)&xs[r * XS_STRIDE + c4] = af[fidx];
        }
    }
    __syncthreads();
    // LayerNorm: 4 adjacent lanes per row, shuffle-combined
    {
        const int r = t >> 2, sub = t & 3;
        float s = 0.f, s2 = 0.f;
        #pragma unroll 8
        for (int j = 0; j < 32; ++j) {
            float x = xs[r * XS_STRIDE + sub * 32 + j];
            s += x; s2 += x * x;
        }
        s += __shfl_xor(s, 1); s2 += __shfl_xor(s2, 1);
        s += __shfl_xor(s, 2); s2 += __shfl_xor(s2, 2);
        const float mu  = s * (1.f / 128.f);
        const float inv = rsqrtf(fmaxf(s2 * (1.f / 128.f) - mu * mu, 0.f) + LN_EPS);
        #pragma unroll 8
        for (int j = 0; j < 32; ++j) {
            int c = sub * 32 + j;
            float x = xs[r * XS_STRIDE + c];
            xs[r * XS_STRIDE + c] = (x - mu) * inv * ln_g[c] + ln_b[c];
        }
    }
    __syncthreads();

    const float* W[4] = {wq, wk, wv, wg};
    float*       O[4] = {qo, ko, vo, go};
    const int c4 = (t & 31) << 2;    // output column group (float4)
    const int r0 = (t >> 5) << 3;    // 8 rows per thread
    const f4 fzero = {0.f, 0.f, 0.f, 0.f};

    for (int m = 0; m < 4; ++m) {
        f4 acc[8];
        #pragma unroll
        for (int jj = 0; jj < 8; ++jj) acc[jj] = fzero;
        for (int half = 0; half < 2; ++half) {
            __syncthreads();   // protect ws from previous readers
            {
                const f4* wf = (const f4*)(W[m] + half * 64 * 128);
                f4* wsf = (f4*)ws;
                #pragma unroll
                for (int j = 0; j < 8; ++j) wsf[t + j * 256] = wf[t + j * 256];
            }
            __syncthreads();
            const int cbase = half * 64;
            for (int c0 = 0; c0 < 64; c0 += 4) {
                f4 xr[8];
                #pragma unroll
                for (int jj = 0; jj < 8; ++jj)
                    xr[jj] = *(const f4*)&xs[(r0 + jj) * XS_STRIDE + cbase + c0];
                #pragma unroll
                for (int u = 0; u < 4; ++u) {
                    f4 w = *(const f4*)&ws[(c0 + u) * 128 + c4];
                    #pragma unroll
                    for (int jj = 0; jj < 8; ++jj)
                        acc[jj] += xr[jj][u] * w;
                }
            }
        }
        if (m == 0) {
            #pragma unroll
            for (int jj = 0; jj < 8; ++jj) acc[jj] *= QK_SCALE;
        }
        if (m == 3) {  // gate: sigmoid(x@wg + bg)
            const f4 bgv = *(const f4*)&bg[c4];
            #pragma unroll
            for (int jj = 0; jj < 8; ++jj) {
                f4 a = acc[jj] + bgv;
                f4 r;
                r.x = 1.f / (1.f + __expf(-a.x));
                r.y = 1.f / (1.f + __expf(-a.y));
                r.z = 1.f / (1.f + __expf(-a.z));
                r.w = 1.f / (1.f + __expf(-a.w));
                acc[jj] = r;
            }
        }
        #pragma unroll
        for (int jj = 0; jj < 8; ++jj)
            *(f4*)&O[m][(p0 + r0 + jj) * HDIM + c4] = acc[jj];
    }

    // pair bias: b2d[p][h] = sum_c x[p][c] * w2d[c][h]
    {
        const int r = t >> 2, h = t & 3;
        float s = 0.f;
        for (int c = 0; c < 128; ++c)
            s += xs[r * XS_STRIDE + c] * w2d[c * 4 + h];
        b2d[(p0 + r) * 4 + h] = s;
    }
}

// ---------------- Kernel 2: per-(row, head, q-tile) attention ----------------
__global__ __launch_bounds__(256)
void k_attn(const float* __restrict__ qi, const float* __restrict__ ki,
            const float* __restrict__ vi, const float* __restrict__ b2d,
            const float* __restrict__ mask, float* __restrict__ oo)
{
    __shared__ float k_s[NN * KS];     // 36.9 KB (reused as PV partial buffer)
    __shared__ float v_s[NN * KS];     // 36.9 KB
    __shared__ float lt[NN * KS];      // 36.9 KB transposed logits lt[k][q]
    __shared__ float q_s[32 * KS];     // 4.6 KB
    __shared__ float mb[NN];
    __shared__ float row_inv[32];

    const int t  = threadIdx.x;
    const int bx = blockIdx.x;
    const int i  = bx >> 5;
    const int h  = (bx >> 3) & 3;
    const int qt = bx & 7;
    const long base = (long)i * NN * HDIM + h * DD;

    #pragma unroll
    for (int j = 0; j < 8; ++j) {
        int fidx = t + j * 256;
        int kk = fidx >> 3, d4 = (fidx & 7) << 2;
        *(f4*)&k_s[kk * KS + d4] = *(const f4*)&ki[base + (long)kk * HDIM + d4];
        *(f4*)&v_s[kk * KS + d4] = *(const f4*)&vi[base + (long)kk * HDIM + d4];
    }
    {
        int qq = t >> 3, d4 = (t & 7) << 2;
        *(f4*)&q_s[qq * KS + d4] = *(const f4*)&qi[base + (long)(qt * 32 + qq) * HDIM + d4];
    }
    mb[t] = 1e9f * (mask[i * NN + t] - 1.f);
    __syncthreads();

    // QK^T: each thread 4 q x 8 k, writes transposed logits (+mask bias + pair bias)
    {
        const int q0 = (t >> 5) << 2;  // 0..28
        const int kb = t & 31;
        float acc[8][4] = {};
        for (int c0 = 0; c0 < 32; c0 += 4) {
            f4 qv[4], kv[8];
            #pragma unroll
            for (int u = 0; u < 4; ++u)
                qv[u] = *(const f4*)&q_s[(q0 + u) * KS + c0];
            #pragma unroll
            for (int j = 0; j < 8; ++j)
                kv[j] = *(const f4*)&k_s[(kb + 32 * j) * KS + c0];
            #pragma unroll
            for (int j = 0; j < 8; ++j) {
                #pragma unroll
                for (int u = 0; u < 4; ++u)
                    acc[j][u] += qv[u].x * kv[j].x + qv[u].y * kv[j].y
                               + qv[u].z * kv[j].z + qv[u].w * kv[j].w;
            }
        }
        const int qg0 = qt * 32 + q0;
        #pragma unroll
        for (int j = 0; j < 8; ++j) {
            const int kk = kb + 32 * j;
            const float m_b = mb[kk];
            f4 outv;
            #pragma unroll
            for (int u = 0; u < 4; ++u)
                outv[u] = acc[j][u] + m_b + b2d[((long)(qg0 + u) * NN + kk) * HH + h];
            *(f4*)&lt[kk * KS + q0] = outv;
        }
    }
    __syncthreads();

    // softmax along k for each q row (8 adjacent lanes per row)
    {
        const int sq = t >> 3, sub = t & 7;
        float mx = -1e30f;
        #pragma unroll 4
        for (int m2 = 0; m2 < 32; ++m2)
            mx = fmaxf(mx, lt[(sub + 8 * m2) * KS + sq]);
        mx = fmaxf(mx, __shfl_xor(mx, 1));
        mx = fmaxf(mx, __shfl_xor(mx, 2));
        mx = fmaxf(mx, __shfl_xor(mx, 4));
        float sum = 0.f;
        #pragma unroll 4
        for (int m2 = 0; m2 < 32; ++m2) {
            const int idx = (sub + 8 * m2) * KS + sq;
            float e = __expf(lt[idx] - mx);
            lt[idx] = e;
            sum += e;
        }
        sum += __shfl_xor(sum, 1);
        sum += __shfl_xor(sum, 2);
        sum += __shfl_xor(sum, 4);
        if (sub == 0) row_inv[sq] = 1.f / sum;
    }
    __syncthreads();

    // PV: k split across 8 groups, 8q x 4d register tile per thread
    {
        const int kg = t >> 5;
        const int l5 = t & 31;
        const int d0 = (l5 & 7) << 2;
        const int q0 = (l5 >> 3) << 3;  // 0,8,16,24
        const f4 fzero = {0.f, 0.f, 0.f, 0.f};
        f4 acc[8];
        #pragma unroll
        for (int jj = 0; jj < 8; ++jj) acc[jj] = fzero;
        for (int kidx = 0; kidx < 32; ++kidx) {
            const int kk = (kg << 5) + kidx;
            const f4 vv = *(const f4*)&v_s[kk * KS + d0];
            const f4 a0 = *(const f4*)&lt[kk * KS + q0];
            const f4 a1 = *(const f4*)&lt[kk * KS + q0 + 4];
            acc[0] += a0.x * vv; acc[1] += a0.y * vv;
            acc[2] += a0.z * vv; acc[3] += a0.w * vv;
            acc[4] += a1.x * vv; acc[5] += a1.y * vv;
            acc[6] += a1.z * vv; acc[7] += a1.w * vv;
        }
        float* part = k_s;  // k_s no longer needed
        #pragma unroll
        for (int jj = 0; jj < 8; ++jj)
            *(f4*)&part[(kg * 32 + q0 + jj) * KS + d0] = acc[jj];
    }
    __syncthreads();
    // reduce the 8 k-group partials, normalize, store o
    {
        const int qq = t >> 3, d0 = (t & 7) << 2;
        const float* part = k_s;
        f4 s = {0.f, 0.f, 0.f, 0.f};
        #pragma unroll
        for (int kg = 0; kg < 8; ++kg)
            s += *(const f4*)&part[(kg * 32 + qq) * KS + d0];
        s *= row_inv[qq];
        *(f4*)&oo[base + (long)(qt * 32 + qq) * HDIM + d0] = s;
    }
}

// ---------------- Kernel 3: gate-multiply + output projection ----------------
__global__ __launch_bounds__(256)
void k_out(const float* __restrict__ oi, const float* __restrict__ gi,
           const float* __restrict__ wo, const float* __restrict__ bo,
           float* __restrict__ out)
{
    __shared__ float os[64 * XS_STRIDE];
    __shared__ float ws[64 * 128];
    const int t = threadIdx.x;
    const long p0 = (long)blockIdx.x * 64;

    #pragma unroll
    for (int j = 0; j < 8; ++j) {
        int fidx = t + j * 256;
        int r = fidx >> 5, c4v = (fidx & 31) << 2;
        f4 ov = *(const f4*)&oi[(p0 + r) * HDIM + c4v];
        f4 gv = *(const f4*)&gi[(p0 + r) * HDIM + c4v];
        *(f4*)&os[r * XS_STRIDE + c4v] = ov * gv;   // g already sigmoid'd
    }

    const int c4 = (t & 31) << 2;
    const int r0 = (t >> 5) << 3;
    const f4 fzero = {0.f, 0.f, 0.f, 0.f};
    f4 acc[8];
    #pragma unroll
    for (int jj = 0; jj < 8; ++jj) acc[jj] = fzero;

    for (int half = 0; half < 2; ++half) {
        __syncthreads();
        {
            const f4* wf = (const f4*)(wo + half * 64 * 128);
            f4* wsf = (f4*)ws;
            #pragma unroll
            for (int j = 0; j < 8; ++j) wsf[t + j * 256] = wf[t + j * 256];
        }
        __syncthreads();
        const int cbase = half * 64;
        for (int c0 = 0; c0 < 64; c0 += 4) {
            f4 xr[8];
            #pragma unroll
            for (int jj = 0; jj < 8; ++jj)
                xr[jj] = *(const f4*)&os[(r0 + jj) * XS_STRIDE + cbase + c0];
            #pragma unroll
            for (int u = 0; u < 4; ++u) {
                f4 w = *(const f4*)&ws[(c0 + u) * 128 + c4];
                #pragma unroll
                for (int jj = 0; jj < 8; ++jj)
                    acc[jj] += xr[jj][u] * w;
            }
        }
    }
    const f4 bov = *(const f4*)&bo[c4];
    #pragma unroll
    for (int jj = 0; jj < 8; ++jj)
        *(f4*)&out[(p0 + r0 + jj) * HDIM + c4] = acc[jj] + bov;
}

extern "C" void kernel_launch(void* const* d_in, const int* in_sizes, int n_in,
                              void* d_out, int out_size, void* d_ws, size_t ws_size,
                              hipStream_t stream) {
    const float* act  = (const float*)d_in[0];
    const float* mask = (const float*)d_in[1];
    const float* ln_g = (const float*)d_in[2];
    const float* ln_b = (const float*)d_in[3];
    const float* w2d  = (const float*)d_in[4];
    const float* wq   = (const float*)d_in[5];
    const float* wk   = (const float*)d_in[6];
    const float* wv   = (const float*)d_in[7];
    const float* wg   = (const float*)d_in[8];
    const float* bg   = (const float*)d_in[9];
    const float* wo   = (const float*)d_in[10];
    const float* bo   = (const float*)d_in[11];
    float* out = (float*)d_out;

    char* ws = (char*)d_ws;
    const size_t PSZ = (size_t)65536 * 128 * sizeof(float);  // 33.55 MB per tensor
    float* q   = (float*)(ws);
    float* k   = (float*)(ws + PSZ);
    float* v   = (float*)(ws + 2 * PSZ);
    float* g   = (float*)(ws + 3 * PSZ);
    float* o   = (float*)(ws + 4 * PSZ);
    float* b2d = (float*)(ws + 5 * PSZ);                      // +1 MB

    k_proj<<<1024, 256, 0, stream>>>(act, ln_g, ln_b, wq, wk, wv, wg, w2d, bg,
                                     q, k, v, g, b2d);
    k_attn<<<8192, 256, 0, stream>>>(q, k, v, b2d, mask, o);
    k_out <<<1024, 256, 0, stream>>>(o, g, wo, bo, out);
}

// Round 2
// 196.793 us; speedup vs baseline: 2.5558x; 2.5558x over previous
//
#include <hip/hip_runtime.h>

#define QK_SCALE 0.17677669529663689f  // 1/sqrt(32)

typedef float f4 __attribute__((ext_vector_type(4)));
typedef short bf16x8 __attribute__((ext_vector_type(8)));
typedef float f32x4 __attribute__((ext_vector_type(4)));
typedef unsigned short us4 __attribute__((ext_vector_type(4)));

__device__ __forceinline__ unsigned short f2bf(float x){
  unsigned int u = __float_as_uint(x);
  u += 0x7fffu + ((u >> 16) & 1u);
  return (unsigned short)(u >> 16);
}
__device__ __forceinline__ float bf2f(unsigned short h){
  return __uint_as_float(((unsigned int)h) << 16);
}
__device__ __forceinline__ f32x4 mfma16(bf16x8 a, bf16x8 b, f32x4 c){
  return __builtin_amdgcn_mfma_f32_16x16x32_bf16(a, b, c, 0, 0, 0);
}
__device__ __forceinline__ void gload_lds16(const void* g, void* s){
  __builtin_amdgcn_global_load_lds(
      (const __attribute__((address_space(1))) unsigned int*)g,
      (__attribute__((address_space(3))) unsigned int*)s, 16, 0, 0);
}

// ---------------- Kernel 0: pack weights into MFMA B-fragment order ----------------
// layout per matrix (K=128, N=128): [nt(8)][kt(4)][hl(2)][lane(64)][e(8)] bf16
// value = W[kt*32 + (lane>>4)*8 + e][nt*16 + (lane&15)]  (wq pre-scaled)
__global__ __launch_bounds__(256)
void k_prep(const float* __restrict__ wq, const float* __restrict__ wk,
            const float* __restrict__ wv, const float* __restrict__ wg,
            const float* __restrict__ wo, unsigned short* __restrict__ pk)
{
  const int m = blockIdx.x;
  const float* W = (m==0)? wq : (m==1)? wk : (m==2)? wv : (m==3)? wg : wo;
  const float scale = (m==0)? QK_SCALE : 1.0f;
  unsigned short* dst = pk + (long)m * 32768;
  for (int ent = threadIdx.x; ent < 2048; ent += 256){
    const int l = ent & 63, ktn = ent >> 6;
    const int kt = ktn & 3, nt = ktn >> 2;
    unsigned short* ph = dst + ((nt*4 + kt)*2 + 0)*512 + l*8;
    unsigned short* pl = dst + ((nt*4 + kt)*2 + 1)*512 + l*8;
    #pragma unroll
    for (int e = 0; e < 8; ++e){
      const int row = kt*32 + (l>>4)*8 + e;
      const int col = nt*16 + (l&15);
      float v = W[row*128 + col] * scale;
      unsigned short hh = f2bf(v);
      ph[e] = hh;
      pl[e] = f2bf(v - bf2f(hh));
    }
  }
}

// ---------------- Kernel 1: LN + q/k/v/g projections (split-bf16 MFMA) + pair bias ----
__global__ __launch_bounds__(512)
void k_proj(const float* __restrict__ act, const float* __restrict__ ln_g,
            const float* __restrict__ ln_b, const float* __restrict__ w2d,
            const unsigned short* __restrict__ pk, const float* __restrict__ bg,
            unsigned short* __restrict__ qh, unsigned short* __restrict__ ql,
            unsigned short* __restrict__ kh, unsigned short* __restrict__ kl,
            unsigned short* __restrict__ vth, unsigned short* __restrict__ vtl,
            float* __restrict__ gout, float* __restrict__ b2d)
{
  __shared__ float xs[128*132];            // 67.6 KB LN'd activations
  __shared__ unsigned short bst[2*8*512];  // 16 KB B-fragment double buffer
  const int t = threadIdx.x;
  const int w = t >> 6, l = t & 63;
  const int g16 = l >> 4, c = l & 15;
  const long p0 = (long)blockIdx.x * 128;
  const int bi = (int)(p0 >> 8);

  { // load 128 rows x 128 ch
    const f4* af = (const f4*)(act + p0*128);
    #pragma unroll
    for (int j = 0; j < 8; ++j){
      int fi = t + j*512;
      int r = fi >> 5, c4 = (fi & 31) << 2;
      *(f4*)&xs[r*132 + c4] = af[fi];
    }
  }
  __syncthreads();
  { // LayerNorm, 4 lanes/row
    const int r = t >> 2, sub = t & 3;
    float s = 0.f, s2 = 0.f;
    #pragma unroll 8
    for (int j = 0; j < 32; ++j){ float x = xs[r*132 + sub*32 + j]; s += x; s2 += x*x; }
    s += __shfl_xor(s,1); s2 += __shfl_xor(s2,1);
    s += __shfl_xor(s,2); s2 += __shfl_xor(s2,2);
    const float mu = s * (1.f/128.f);
    const float iv = rsqrtf(fmaxf(s2*(1.f/128.f) - mu*mu, 0.f) + 1e-5f);
    #pragma unroll 8
    for (int j = 0; j < 32; ++j){
      int cc = sub*32 + j;
      float x = xs[r*132 + cc];
      xs[r*132 + cc] = (x - mu)*iv*ln_g[cc] + ln_b[cc];
    }
  }
  __syncthreads();

  // A fragments (16 rows per wave), split hi/lo
  bf16x8 ah[4], al[4];
  #pragma unroll
  for (int kt = 0; kt < 4; ++kt){
    const float* xp = &xs[(w*16 + c)*132 + kt*32 + g16*8];
    f4 x0 = *(const f4*)xp; f4 x1 = *(const f4*)(xp + 4);
    bf16x8 hv, lv;
    #pragma unroll
    for (int e = 0; e < 8; ++e){
      float v = (e < 4) ? x0[e] : x1[e-4];
      unsigned short hh = f2bf(v);
      hv[e] = (short)hh;
      lv[e] = (short)f2bf(v - bf2f(hh));
    }
    ah[kt] = hv; al[kt] = lv;
  }

  { // pair bias b2d[h][p] = sum_c x[p][c]*w2d[c][h]
    const int r = t >> 2, hh = t & 3;
    float s = 0.f;
    #pragma unroll 8
    for (int cc = 0; cc < 128; ++cc) s += xs[r*132 + cc] * w2d[cc*4 + hh];
    b2d[(long)hh*65536 + p0 + r] = s;
  }

  // GEMM over 32 N-tiles (q:0-7, k:8-15, v:16-23, g:24-31), dbuf B staging
  gload_lds16(pk + (0*8 + w)*512 + l*8, bst + w*512);
  asm volatile("s_waitcnt vmcnt(0)" ::: "memory");
  __syncthreads();

  for (int nt = 0; nt < 32; ++nt){
    if (nt < 31)
      gload_lds16(pk + ((nt+1)*8 + w)*512 + l*8, bst + ((nt+1)&1)*4096 + w*512);
    const unsigned short* bb = bst + (nt&1)*4096;
    f32x4 acc = {0.f,0.f,0.f,0.f};
    #pragma unroll
    for (int kt = 0; kt < 4; ++kt){
      bf16x8 bh = *(const bf16x8*)(bb + (kt*2 + 0)*512 + l*8);
      bf16x8 bl = *(const bf16x8*)(bb + (kt*2 + 1)*512 + l*8);
      acc = mfma16(ah[kt], bh, acc);
      acc = mfma16(ah[kt], bl, acc);
      acc = mfma16(al[kt], bh, acc);
    }
    const int m = nt >> 3, ntm = nt & 7;
    if (m <= 1){           // q or k: bf16 hi/lo, layout [(i*4+h)*8192 + q*32 + d]
      const int hsel = ntm >> 1, d0 = (ntm & 1)*16;
      unsigned short* ph = m ? kh : qh;
      unsigned short* pl = m ? kl : ql;
      const int qb = (int)(p0 & 255) + w*16 + g16*4;
      const long ob = ((long)bi*4 + hsel)*8192 + (long)qb*32 + d0 + c;
      #pragma unroll
      for (int j = 0; j < 4; ++j){
        unsigned short hh = f2bf(acc[j]);
        ph[ob + j*32] = hh;
        pl[ob + j*32] = f2bf(acc[j] - bf2f(hh));
      }
    } else if (m == 2){    // v: transposed [d][kv], XOR-swizzled global image
      const int hsel = ntm >> 1;
      const int d = (ntm & 1)*16 + c;
      us4 v4h, v4l;
      #pragma unroll
      for (int j = 0; j < 4; ++j){
        unsigned short hh = f2bf(acc[j]);
        v4h[j] = hh;
        v4l[j] = f2bf(acc[j] - bf2f(hh));
      }
      const int kv0 = (int)(p0 & 255) + w*16 + g16*4;
      const long bbyt = ((long)bi*4 + hsel)*16384;
      const int vb = (d*512 + kv0*2) ^ ((d & 7) << 4);
      *(us4*)((char*)vth + bbyt + vb) = v4h;
      *(us4*)((char*)vtl + bbyt + vb) = v4l;
    } else {               // g: sigmoid(acc + bg), fp32 [p][128]
      const float bgv = bg[ntm*16 + c];
      #pragma unroll
      for (int j = 0; j < 4; ++j){
        float gv = acc[j] + bgv;
        gv = 1.f/(1.f + __expf(-gv));
        gout[(p0 + w*16 + g16*4 + j)*128 + ntm*16 + c] = gv;
      }
    }
    asm volatile("s_waitcnt vmcnt(0)" ::: "memory");
    __syncthreads();
  }
}

// ---------------- Kernel 2: attention, block = (i, h), 8 waves x 32 q-rows ----------
__global__ __launch_bounds__(512)
void k_attn(const unsigned short* __restrict__ qhg, const unsigned short* __restrict__ qlg,
            const unsigned short* __restrict__ khg, const unsigned short* __restrict__ klg,
            const unsigned short* __restrict__ vhg, const unsigned short* __restrict__ vlg,
            const float* __restrict__ b2d, const float* __restrict__ mask,
            float* __restrict__ o)
{
  __shared__ unsigned short kh_s[256*32];   // 16 KB each
  __shared__ unsigned short kl_s[256*32];
  __shared__ unsigned short vh_s[32*256];   // swizzled image
  __shared__ unsigned short vl_s[32*256];
  __shared__ unsigned short p_s[8*16*264];  // 67.6 KB: per-wave P tiles (padded)
  __shared__ float mb_s[256];

  const int t = threadIdx.x;
  const int w = t >> 6, l = t & 63;
  const int bi = blockIdx.x >> 2, h = blockIdx.x & 3;
  const long base = ((long)bi*4 + h) * 8192;
  const int g16 = l >> 4, c = l & 15;

  { // stage K(hi,lo) + V^T(hi,lo): 64 x 1KB chunks, 8 per wave
    const unsigned short* gs = (w < 2) ? khg + base : (w < 4) ? klg + base
                             : (w < 6) ? vhg + base : vlg + base;
    unsigned short* ls = (w < 2) ? kh_s : (w < 4) ? kl_s : (w < 6) ? vh_s : vl_s;
    const int c16b = (w & 1) * 8;
    #pragma unroll
    for (int cc = 0; cc < 8; ++cc){
      const int c16 = c16b + cc;
      gload_lds16(gs + c16*512 + l*8, ls + c16*512);
    }
  }
  if (t < 256) mb_s[t] = 1e9f * (mask[bi*256 + t] - 1.0f);
  asm volatile("s_waitcnt vmcnt(0)" ::: "memory");
  __syncthreads();

  // Q fragments for the wave's two 16-row tiles
  bf16x8 qfh[2], qfl[2];
  #pragma unroll
  for (int im = 0; im < 2; ++im){
    const int q0 = w*32 + im*16;
    qfh[im] = *(const bf16x8*)(qhg + base + (q0 + c)*32 + g16*8);
    qfl[im] = *(const bf16x8*)(qlg + base + (q0 + c)*32 + g16*8);
  }

  unsigned short* pw = p_s + w*(16*264);

  for (int im = 0; im < 2; ++im){
    const int q0 = w*32 + im*16;
    // ---- S = Q K^T + bias (bias as MFMA C-init)
    f32x4 sa[16];
    #pragma unroll
    for (int nt = 0; nt < 16; ++nt){
      const int kcol = nt*16 + c;
      const float mbv = mb_s[kcol];
      const float* bp = b2d + (long)h*65536 + (long)(q0 + g16*4)*256 + kcol;
      f32x4 a;
      a[0] = mbv + bp[0];   a[1] = mbv + bp[256];
      a[2] = mbv + bp[512]; a[3] = mbv + bp[768];
      bf16x8 kf  = *(const bf16x8*)(kh_s + kcol*32 + g16*8);
      bf16x8 kfl = *(const bf16x8*)(kl_s + kcol*32 + g16*8);
      a = mfma16(qfh[im], kf,  a);
      a = mfma16(qfh[im], kfl, a);
      a = mfma16(qfl[im], kf,  a);
      sa[nt] = a;
    }
    // ---- softmax (rows live in 16-lane groups)
    float mx0=-3e38f, mx1=-3e38f, mx2=-3e38f, mx3=-3e38f;
    #pragma unroll
    for (int nt = 0; nt < 16; ++nt){
      mx0 = fmaxf(mx0, sa[nt][0]); mx1 = fmaxf(mx1, sa[nt][1]);
      mx2 = fmaxf(mx2, sa[nt][2]); mx3 = fmaxf(mx3, sa[nt][3]);
    }
    #pragma unroll
    for (int d = 1; d < 16; d <<= 1){
      mx0 = fmaxf(mx0, __shfl_xor(mx0, d)); mx1 = fmaxf(mx1, __shfl_xor(mx1, d));
      mx2 = fmaxf(mx2, __shfl_xor(mx2, d)); mx3 = fmaxf(mx3, __shfl_xor(mx3, d));
    }
    float s0=0.f, s1=0.f, s2=0.f, s3=0.f;
    #pragma unroll
    for (int nt = 0; nt < 16; ++nt){
      float e0 = __expf(sa[nt][0]-mx0), e1 = __expf(sa[nt][1]-mx1);
      float e2 = __expf(sa[nt][2]-mx2), e3 = __expf(sa[nt][3]-mx3);
      s0 += e0; s1 += e1; s2 += e2; s3 += e3;
      const int cb = nt*16 + c;
      pw[(4*g16+0)*264 + cb] = f2bf(e0);
      pw[(4*g16+1)*264 + cb] = f2bf(e1);
      pw[(4*g16+2)*264 + cb] = f2bf(e2);
      pw[(4*g16+3)*264 + cb] = f2bf(e3);
    }
    #pragma unroll
    for (int d = 1; d < 16; d <<= 1){
      s0 += __shfl_xor(s0, d); s1 += __shfl_xor(s1, d);
      s2 += __shfl_xor(s2, d); s3 += __shfl_xor(s3, d);
    }
    const float inv0 = 1.f/s0, inv1 = 1.f/s1, inv2 = 1.f/s2, inv3 = 1.f/s3;
    asm volatile("s_waitcnt lgkmcnt(0)" ::: "memory");
    __builtin_amdgcn_sched_barrier(0);
    // ---- O = P V (P bf16, V split)
    f32x4 oa0 = {0.f,0.f,0.f,0.f}, oa1 = {0.f,0.f,0.f,0.f};
    #pragma unroll
    for (int kt = 0; kt < 8; ++kt){
      bf16x8 pf = *(const bf16x8*)(pw + c*264 + kt*32 + g16*8);
      const int vb0 = (( c      *512 + kt*64 + g16*16) ^ ((c & 7) << 4));
      const int vb1 = (((16 + c)*512 + kt*64 + g16*16) ^ ((c & 7) << 4));
      bf16x8 vh0 = *(const bf16x8*)((const char*)vh_s + vb0);
      bf16x8 vl0 = *(const bf16x8*)((const char*)vl_s + vb0);
      bf16x8 vh1 = *(const bf16x8*)((const char*)vh_s + vb1);
      bf16x8 vl1 = *(const bf16x8*)((const char*)vl_s + vb1);
      oa0 = mfma16(pf, vh0, oa0); oa0 = mfma16(pf, vl0, oa0);
      oa1 = mfma16(pf, vh1, oa1); oa1 = mfma16(pf, vl1, oa1);
    }
    float* ob = o + ((long)bi*256 + q0 + g16*4)*128 + h*32;
    ob[0*128 + c]      = oa0[0]*inv0; ob[1*128 + c]      = oa0[1]*inv1;
    ob[2*128 + c]      = oa0[2]*inv2; ob[3*128 + c]      = oa0[3]*inv3;
    ob[0*128 + 16 + c] = oa1[0]*inv0; ob[1*128 + 16 + c] = oa1[1]*inv1;
    ob[2*128 + 16 + c] = oa1[2]*inv2; ob[3*128 + 16 + c] = oa1[3]*inv3;
  }
}

// ---------------- Kernel 3: out = (o * g) @ wo + bo (split-bf16 MFMA) ---------------
__global__ __launch_bounds__(512)
void k_out(const float* __restrict__ oi, const float* __restrict__ gi,
           const unsigned short* __restrict__ pko, const float* __restrict__ bo,
           float* __restrict__ out)
{
  __shared__ float xs[128*132];
  __shared__ unsigned short bst[2*8*512];
  const int t = threadIdx.x;
  const int w = t >> 6, l = t & 63;
  const int g16 = l >> 4, c = l & 15;
  const long p0 = (long)blockIdx.x * 128;

  {
    #pragma unroll
    for (int j = 0; j < 8; ++j){
      int fi = t + j*512;
      int r = fi >> 5, c4 = (fi & 31) << 2;
      f4 ov = *(const f4*)(oi + (p0 + r)*128 + c4);
      f4 gv = *(const f4*)(gi + (p0 + r)*128 + c4);
      *(f4*)&xs[r*132 + c4] = ov * gv;
    }
  }
  __syncthreads();

  bf16x8 ah[4], al[4];
  #pragma unroll
  for (int kt = 0; kt < 4; ++kt){
    const float* xp = &xs[(w*16 + c)*132 + kt*32 + g16*8];
    f4 x0 = *(const f4*)xp; f4 x1 = *(const f4*)(xp + 4);
    bf16x8 hv, lv;
    #pragma unroll
    for (int e = 0; e < 8; ++e){
      float v = (e < 4) ? x0[e] : x1[e-4];
      unsigned short hh = f2bf(v);
      hv[e] = (short)hh;
      lv[e] = (short)f2bf(v - bf2f(hh));
    }
    ah[kt] = hv; al[kt] = lv;
  }

  gload_lds16(pko + (0*8 + w)*512 + l*8, bst + w*512);
  asm volatile("s_waitcnt vmcnt(0)" ::: "memory");
  __syncthreads();

  for (int nt = 0; nt < 8; ++nt){
    if (nt < 7)
      gload_lds16(pko + ((nt+1)*8 + w)*512 + l*8, bst + ((nt+1)&1)*4096 + w*512);
    const unsigned short* bb = bst + (nt&1)*4096;
    f32x4 acc = {0.f,0.f,0.f,0.f};
    #pragma unroll
    for (int kt = 0; kt < 4; ++kt){
      bf16x8 bh = *(const bf16x8*)(bb + (kt*2 + 0)*512 + l*8);
      bf16x8 bl = *(const bf16x8*)(bb + (kt*2 + 1)*512 + l*8);
      acc = mfma16(ah[kt], bh, acc);
      acc = mfma16(ah[kt], bl, acc);
      acc = mfma16(al[kt], bh, acc);
    }
    const float bov = bo[nt*16 + c];
    #pragma unroll
    for (int j = 0; j < 4; ++j)
      out[(p0 + w*16 + g16*4 + j)*128 + nt*16 + c] = acc[j] + bov;
    asm volatile("s_waitcnt vmcnt(0)" ::: "memory");
    __syncthreads();
  }
}

extern "C" void kernel_launch(void* const* d_in, const int* in_sizes, int n_in,
                              void* d_out, int out_size, void* d_ws, size_t ws_size,
                              hipStream_t stream) {
  const float* act  = (const float*)d_in[0];
  const float* mask = (const float*)d_in[1];
  const float* ln_g = (const float*)d_in[2];
  const float* ln_b = (const float*)d_in[3];
  const float* w2d  = (const float*)d_in[4];
  const float* wq   = (const float*)d_in[5];
  const float* wk   = (const float*)d_in[6];
  const float* wv   = (const float*)d_in[7];
  const float* wg   = (const float*)d_in[8];
  const float* bg   = (const float*)d_in[9];
  const float* wo   = (const float*)d_in[10];
  const float* bo   = (const float*)d_in[11];
  float* out = (float*)d_out;

  char* ws = (char*)d_ws;
  unsigned short* qh  = (unsigned short*)(ws);
  unsigned short* ql  = (unsigned short*)(ws + 16777216L);
  unsigned short* kh  = (unsigned short*)(ws + 33554432L);
  unsigned short* kl  = (unsigned short*)(ws + 50331648L);
  unsigned short* vth = (unsigned short*)(ws + 67108864L);
  unsigned short* vtl = (unsigned short*)(ws + 83886080L);
  float* g   = (float*)(ws + 100663296L);
  float* o   = (float*)(ws + 134217728L);
  float* b2d = (float*)(ws + 167772160L);
  unsigned short* pk = (unsigned short*)(ws + 168820736L);

  k_prep<<<5, 256, 0, stream>>>(wq, wk, wv, wg, wo, pk);
  k_proj<<<512, 512, 0, stream>>>(act, ln_g, ln_b, w2d, pk, bg,
                                  qh, ql, kh, kl, vth, vtl, g, b2d);
  k_attn<<<1024, 512, 0, stream>>>(qh, ql, kh, kl, vth, vtl, b2d, mask, o);
  k_out<<<512, 512, 0, stream>>>(o, g, pk + 4*32768, bo, out);
}

// Round 4
// 127.595 us; speedup vs baseline: 3.9419x; 1.5423x over previous
//
#include <hip/hip_runtime.h>

#define QK_SCALE 0.17677669529663689f  // 1/sqrt(32)

typedef float f4 __attribute__((ext_vector_type(4)));
typedef short bf16x8 __attribute__((ext_vector_type(8)));
typedef float f32x4 __attribute__((ext_vector_type(4)));
typedef unsigned short us4 __attribute__((ext_vector_type(4)));

__device__ __forceinline__ unsigned short f2bf(float x){
  unsigned int u = __float_as_uint(x);
  u += 0x7fffu + ((u >> 16) & 1u);
  return (unsigned short)(u >> 16);
}
__device__ __forceinline__ float bf2f(unsigned short h){
  return __uint_as_float(((unsigned int)h) << 16);
}
__device__ __forceinline__ f32x4 mfma16(bf16x8 a, bf16x8 b, f32x4 c){
  return __builtin_amdgcn_mfma_f32_16x16x32_bf16(a, b, c, 0, 0, 0);
}
__device__ __forceinline__ void gload_lds16(const void* g, void* s){
  __builtin_amdgcn_global_load_lds(
      (const __attribute__((address_space(1))) unsigned int*)g,
      (__attribute__((address_space(3))) unsigned int*)s, 16, 0, 0);
}

// ---------------- Kernel 0: pack weights into MFMA B-fragment order ----------------
// layout per matrix (K=128, N=128): [nt(8)][kt(4)][hl(2)][lane(64)][e(8)] bf16
// value = W[kt*32 + (lane>>4)*8 + e][nt*16 + (lane&15)]  (wq pre-scaled)
__global__ __launch_bounds__(256)
void k_prep(const float* __restrict__ wq, const float* __restrict__ wk,
            const float* __restrict__ wv, const float* __restrict__ wg,
            const float* __restrict__ wo, unsigned short* __restrict__ pk)
{
  const int m = blockIdx.x;
  const float* W = (m==0)? wq : (m==1)? wk : (m==2)? wv : (m==3)? wg : wo;
  const float scale = (m==0)? QK_SCALE : 1.0f;
  unsigned short* dst = pk + (long)m * 32768;
  for (int ent = threadIdx.x; ent < 2048; ent += 256){
    const int l = ent & 63, ktn = ent >> 6;
    const int kt = ktn & 3, nt = ktn >> 2;
    unsigned short* ph = dst + ((nt*4 + kt)*2 + 0)*512 + l*8;
    unsigned short* pl = dst + ((nt*4 + kt)*2 + 1)*512 + l*8;
    #pragma unroll
    for (int e = 0; e < 8; ++e){
      const int row = kt*32 + (l>>4)*8 + e;
      const int col = nt*16 + (l&15);
      float v = W[row*128 + col] * scale;
      unsigned short hh = f2bf(v);
      ph[e] = hh;
      pl[e] = f2bf(v - bf2f(hh));
    }
  }
}

// ---------------- Kernel 1: LN + q/k/v/g projections + pair bias ----------------
// Outputs: q,k bf16 in MFMA-frag layout [ih][tile16][lane][8]; v bf16 transposed
// XOR-swizzled [ih] image; g = sigmoid(x@wg+bg) bf16 row-major; b2d fp32 [h][65536].
__global__ __launch_bounds__(512, 2)
void k_proj(const float* __restrict__ act, const float* __restrict__ ln_g,
            const float* __restrict__ ln_b, const float* __restrict__ w2d,
            const unsigned short* __restrict__ pk, const float* __restrict__ bg,
            unsigned short* __restrict__ qf, unsigned short* __restrict__ kf,
            unsigned short* __restrict__ vt, unsigned short* __restrict__ gg,
            float* __restrict__ b2d)
{
  __shared__ float xs[128*132];              // 67.6 KB LN'd activations
  __shared__ unsigned short afr[8*4*2*512];  // 64 KB A-fragments hi/lo
  __shared__ unsigned short sc[8*640];       // 10 KB per-wave C->frag bounce
  const int t = threadIdx.x, w = t>>6, l = t&63, g16 = l>>4, c = l&15;
  const long p0 = (long)blockIdx.x * 128;
  const int bi = (int)(p0 >> 8);
  const int qb0 = (int)(p0 & 255);

  { const f4* af = (const f4*)(act + p0*128);
    #pragma unroll
    for (int j = 0; j < 8; ++j){
      int fi = t + j*512, r = fi>>5, c4 = (fi&31)<<2;
      *(f4*)&xs[r*132 + c4] = af[fi];
    } }
  __syncthreads();
  { // LayerNorm, 4 lanes/row
    const int r = t>>2, sub = t&3;
    float s=0.f, s2=0.f;
    #pragma unroll 8
    for (int jj=0; jj<32; ++jj){ float x = xs[r*132+sub*32+jj]; s+=x; s2+=x*x; }
    s += __shfl_xor(s,1); s2 += __shfl_xor(s2,1);
    s += __shfl_xor(s,2); s2 += __shfl_xor(s2,2);
    const float mu = s*(1.f/128.f);
    const float iv = rsqrtf(fmaxf(s2*(1.f/128.f)-mu*mu,0.f)+1e-5f);
    #pragma unroll 8
    for (int jj=0; jj<32; ++jj){
      int cc = sub*32+jj;
      xs[r*132+cc] = (xs[r*132+cc]-mu)*iv*ln_g[cc]+ln_b[cc];
    } }
  __syncthreads();

  // A-fragments: wave w builds row-tile w (rows w*16..w*16+16)
  #pragma unroll
  for (int kt = 0; kt < 4; ++kt){
    const float* xp = &xs[(w*16+c)*132 + kt*32 + g16*8];
    f4 x0 = *(const f4*)xp, x1 = *(const f4*)(xp+4);
    bf16x8 hv, lv;
    #pragma unroll
    for (int e = 0; e < 8; ++e){
      float vvv = (e<4)? x0[e] : x1[e-4];
      unsigned short hh = f2bf(vvv);
      hv[e] = (short)hh; lv[e] = (short)f2bf(vvv - bf2f(hh));
    }
    *(bf16x8*)&afr[((w*4+kt)*2+0)*512 + l*8] = hv;
    *(bf16x8*)&afr[((w*4+kt)*2+1)*512 + l*8] = lv;
  }
  { // pair bias
    const int r = t>>2, hh = t&3;
    float s = 0.f;
    #pragma unroll 8
    for (int cc = 0; cc < 128; ++cc) s += xs[r*132+cc]*w2d[cc*4+hh];
    b2d[hh*65536 + (int)p0 + r] = s;
  }
  __syncthreads();

  unsigned short* scw = sc + w*640;

  #pragma unroll
  for (int pass = 0; pass < 2; ++pass){
    // B-fragments for 2 N-tiles in registers (no LDS, no barriers)
    bf16x8 bh0[4], bl0[4], bh1[4], bl1[4];
    { const int ntg = w*4 + pass*2;
      #pragma unroll
      for (int kt = 0; kt < 4; ++kt){
        bh0[kt] = *(const bf16x8*)(pk + ((ntg*4+kt)*2+0)*512 + l*8);
        bl0[kt] = *(const bf16x8*)(pk + ((ntg*4+kt)*2+1)*512 + l*8);
        bh1[kt] = *(const bf16x8*)(pk + (((ntg+1)*4+kt)*2+0)*512 + l*8);
        bl1[kt] = *(const bf16x8*)(pk + (((ntg+1)*4+kt)*2+1)*512 + l*8);
      } }
    for (int rt = 0; rt < 8; ++rt){
      bf16x8 ah[4], al[4];
      #pragma unroll
      for (int kt = 0; kt < 4; ++kt){
        ah[kt] = *(const bf16x8*)&afr[((rt*4+kt)*2+0)*512 + l*8];
        al[kt] = *(const bf16x8*)&afr[((rt*4+kt)*2+1)*512 + l*8];
      }
      f32x4 a0 = {0.f,0.f,0.f,0.f}, a1 = {0.f,0.f,0.f,0.f};
      #pragma unroll
      for (int kt = 0; kt < 4; ++kt){
        a0 = mfma16(ah[kt], bh0[kt], a0);
        a1 = mfma16(ah[kt], bh1[kt], a1);
        a0 = mfma16(ah[kt], bl0[kt], a0);
        a1 = mfma16(ah[kt], bl1[kt], a1);
        a0 = mfma16(al[kt], bh0[kt], a0);
        a1 = mfma16(al[kt], bh1[kt], a1);
      }
      if (w < 4){           // q/k: C-tile -> frag layout via wave-local bounce
        #pragma unroll
        for (int j = 0; j < 4; ++j){
          scw[(g16*4+j)*40 + c]      = f2bf(a0[j]);
          scw[(g16*4+j)*40 + 16 + c] = f2bf(a1[j]);
        }
        asm volatile("" ::: "memory");  // keep LDS write->read order
        bf16x8 fr = *(const bf16x8*)&scw[c*40 + g16*8];
        const int head = (w&1)*2 + pass;
        unsigned short* dst = (w < 2) ? qf : kf;
        *(bf16x8*)&dst[(((long)bi*4+head)*16 + (qb0>>4) + rt)*512 + l*8] = fr;
        asm volatile("" ::: "memory");  // reads done before next rt's writes
      } else if (w < 6){    // v: transposed swizzled image
        const int ntv0 = (w-4)*4 + pass*2;
        const int kv = qb0 + rt*16 + g16*4;
        #pragma unroll
        for (int np = 0; np < 2; ++np){
          const int colg = (ntv0+np)*16 + c;
          const int head = colg >> 5, d = colg & 31;
          f32x4 aa = np ? a1 : a0;
          us4 v4;
          #pragma unroll
          for (int j = 0; j < 4; ++j) v4[j] = f2bf(aa[j]);
          const int vb = (d*512 + kv*2) ^ ((d&7)<<4);
          *(us4*)((char*)vt + ((long)bi*4+head)*16384 + vb) = v4;
        }
      } else {              // g: sigmoid(x@wg + bg), bf16 row-major
        const int colb = (w-6)*64 + pass*32;
        const int row0 = (int)p0 + rt*16 + g16*4;
        const float bg0 = bg[colb + c];
        const float bg1 = bg[colb + 16 + c];
        #pragma unroll
        for (int j = 0; j < 4; ++j){
          float g0 = 1.f/(1.f + __expf(-(a0[j] + bg0)));
          float g1 = 1.f/(1.f + __expf(-(a1[j] + bg1)));
          gg[(row0+j)*128 + colb + c]      = f2bf(g0);
          gg[(row0+j)*128 + colb + 16 + c] = f2bf(g1);
        }
      }
    }
  }
}

// ---------------- Kernel 2: attention (i,h)-block, 4 waves x 64 q-rows, gate fused --
__global__ __launch_bounds__(256, 2)
void k_attn(const unsigned short* __restrict__ qf, const unsigned short* __restrict__ kfg,
            const unsigned short* __restrict__ vt, const unsigned short* __restrict__ gg,
            const float* __restrict__ b2d, const float* __restrict__ mask,
            float* __restrict__ o)
{
  __shared__ unsigned short k_s[16*512];   // 16 KB K fragments
  __shared__ unsigned short v_s[8192];     // 16 KB V^T swizzled image
  __shared__ unsigned short p_s[4*4224];   // 33 KB per-wave P tiles (stride 264)
  __shared__ float mb_s[256];
  const int t = threadIdx.x, w = t>>6, l = t&63, g16 = l>>4, c = l&15;
  const int bi = blockIdx.x >> 2, h = blockIdx.x & 3;
  const int base = (bi*4+h)*8192;

  #pragma unroll
  for (int cc = 0; cc < 8; ++cc){
    const int ch = w*8 + cc;
    if (ch < 16) gload_lds16(kfg + base + ch*512 + l*8, k_s + ch*512);
    else         gload_lds16(vt + base + (ch-16)*512 + l*8, v_s + (ch-16)*512);
  }
  mb_s[t] = 1e9f * (mask[bi*256 + t] - 1.0f);
  asm volatile("s_waitcnt vmcnt(0)" ::: "memory");
  __syncthreads();

  unsigned short* pw = p_s + w*4224;

  for (int im = 0; im < 4; ++im){
    const int q0 = w*64 + im*16;
    const bf16x8 qfr = *(const bf16x8*)(qf + base + (q0>>4)*512 + l*8);
    // ---- S = Q K^T + bias (bias as C-init)
    f32x4 sa[16];
    #pragma unroll
    for (int nt = 0; nt < 16; ++nt){
      const int kcol = nt*16 + c;
      const float mbv = mb_s[kcol];
      const float* bp = b2d + h*65536 + (q0 + g16*4)*256 + kcol;
      f32x4 ci;
      ci[0]=mbv+bp[0]; ci[1]=mbv+bp[256]; ci[2]=mbv+bp[512]; ci[3]=mbv+bp[768];
      sa[nt] = mfma16(qfr, *(const bf16x8*)(k_s + nt*512 + l*8), ci);
    }
    // ---- softmax (row r = g16*4+j lives across the 16 c-lanes)
    float mx0=-3e38f,mx1=-3e38f,mx2=-3e38f,mx3=-3e38f;
    #pragma unroll
    for (int nt = 0; nt < 16; ++nt){
      mx0 = fmaxf(mx0, sa[nt][0]); mx1 = fmaxf(mx1, sa[nt][1]);
      mx2 = fmaxf(mx2, sa[nt][2]); mx3 = fmaxf(mx3, sa[nt][3]);
    }
    #pragma unroll
    for (int d = 1; d < 16; d <<= 1){
      mx0 = fmaxf(mx0, __shfl_xor(mx0, d)); mx1 = fmaxf(mx1, __shfl_xor(mx1, d));
      mx2 = fmaxf(mx2, __shfl_xor(mx2, d)); mx3 = fmaxf(mx3, __shfl_xor(mx3, d));
    }
    float s0=0.f, s1=0.f, s2=0.f, s3=0.f;
    #pragma unroll
    for (int nt = 0; nt < 16; ++nt){
      float e0 = __expf(sa[nt][0]-mx0), e1 = __expf(sa[nt][1]-mx1);
      float e2 = __expf(sa[nt][2]-mx2), e3 = __expf(sa[nt][3]-mx3);
      s0 += e0; s1 += e1; s2 += e2; s3 += e3;
      const int cb = nt*16 + c;
      pw[(g16*4+0)*264 + cb] = f2bf(e0);
      pw[(g16*4+1)*264 + cb] = f2bf(e1);
      pw[(g16*4+2)*264 + cb] = f2bf(e2);
      pw[(g16*4+3)*264 + cb] = f2bf(e3);
    }
    #pragma unroll
    for (int d = 1; d < 16; d <<= 1){
      s0 += __shfl_xor(s0, d); s1 += __shfl_xor(s1, d);
      s2 += __shfl_xor(s2, d); s3 += __shfl_xor(s3, d);
    }
    float invs[4] = {1.f/s0, 1.f/s1, 1.f/s2, 1.f/s3};
    asm volatile("s_waitcnt lgkmcnt(0)" ::: "memory");
    __builtin_amdgcn_sched_barrier(0);
    // ---- O = P V
    f32x4 oa0 = {0.f,0.f,0.f,0.f}, oa1 = {0.f,0.f,0.f,0.f};
    #pragma unroll
    for (int kt = 0; kt < 8; ++kt){
      bf16x8 pf = *(const bf16x8*)(pw + c*264 + kt*32 + g16*8);
      const int vb0 = ((c*512      + kt*64 + g16*16) ^ ((c&7)<<4));
      const int vb1 = (((16+c)*512 + kt*64 + g16*16) ^ ((c&7)<<4));
      oa0 = mfma16(pf, *(const bf16x8*)((const char*)v_s + vb0), oa0);
      oa1 = mfma16(pf, *(const bf16x8*)((const char*)v_s + vb1), oa1);
    }
    // ---- normalize, gate, store
    const int row0 = bi*256 + q0 + g16*4;
    #pragma unroll
    for (int j = 0; j < 4; ++j){
      float gv0 = bf2f(gg[(row0+j)*128 + h*32 + c]);
      float gv1 = bf2f(gg[(row0+j)*128 + h*32 + 16 + c]);
      o[(row0+j)*128 + h*32 + c]      = oa0[j]*invs[j]*gv0;
      o[(row0+j)*128 + h*32 + 16 + c] = oa1[j]*invs[j]*gv1;
    }
  }
}

// ---------------- Kernel 3: out = o_gated @ wo + bo ----------------
__global__ __launch_bounds__(512, 2)
void k_out(const float* __restrict__ oi, const unsigned short* __restrict__ pko,
           const float* __restrict__ bo, float* __restrict__ out)
{
  __shared__ float xs[128*132];
  __shared__ unsigned short afr[8*4*2*512];
  const int t = threadIdx.x, w = t>>6, l = t&63, g16 = l>>4, c = l&15;
  const long p0 = (long)blockIdx.x * 128;

  { const f4* af = (const f4*)(oi + p0*128);
    #pragma unroll
    for (int j = 0; j < 8; ++j){
      int fi = t + j*512, r = fi>>5, c4 = (fi&31)<<2;
      *(f4*)&xs[r*132 + c4] = af[fi];
    } }
  __syncthreads();
  #pragma unroll
  for (int kt = 0; kt < 4; ++kt){
    const float* xp = &xs[(w*16+c)*132 + kt*32 + g16*8];
    f4 x0 = *(const f4*)xp, x1 = *(const f4*)(xp+4);
    bf16x8 hv, lv;
    #pragma unroll
    for (int e = 0; e < 8; ++e){
      float vvv = (e<4)? x0[e] : x1[e-4];
      unsigned short hh = f2bf(vvv);
      hv[e] = (short)hh; lv[e] = (short)f2bf(vvv - bf2f(hh));
    }
    *(bf16x8*)&afr[((w*4+kt)*2+0)*512 + l*8] = hv;
    *(bf16x8*)&afr[((w*4+kt)*2+1)*512 + l*8] = lv;
  }
  __syncthreads();

  bf16x8 bh[4], bl[4];
  #pragma unroll
  for (int kt = 0; kt < 4; ++kt){
    bh[kt] = *(const bf16x8*)(pko + ((w*4+kt)*2+0)*512 + l*8);
    bl[kt] = *(const bf16x8*)(pko + ((w*4+kt)*2+1)*512 + l*8);
  }
  const float bov = bo[w*16 + c];
  for (int rt = 0; rt < 8; ++rt){
    bf16x8 ah[4], al[4];
    #pragma unroll
    for (int kt = 0; kt < 4; ++kt){
      ah[kt] = *(const bf16x8*)&afr[((rt*4+kt)*2+0)*512 + l*8];
      al[kt] = *(const bf16x8*)&afr[((rt*4+kt)*2+1)*512 + l*8];
    }
    f32x4 a0 = {bov, bov, bov, bov};
    #pragma unroll
    for (int kt = 0; kt < 4; ++kt){
      a0 = mfma16(ah[kt], bh[kt], a0);
      a0 = mfma16(ah[kt], bl[kt], a0);
      a0 = mfma16(al[kt], bh[kt], a0);
    }
    const int row0 = (int)p0 + rt*16 + g16*4;
    #pragma unroll
    for (int j = 0; j < 4; ++j)
      out[(row0+j)*128 + w*16 + c] = a0[j];
  }
}

extern "C" void kernel_launch(void* const* d_in, const int* in_sizes, int n_in,
                              void* d_out, int out_size, void* d_ws, size_t ws_size,
                              hipStream_t stream) {
  const float* act  = (const float*)d_in[0];
  const float* mask = (const float*)d_in[1];
  const float* ln_g = (const float*)d_in[2];
  const float* ln_b = (const float*)d_in[3];
  const float* w2d  = (const float*)d_in[4];
  const float* wq   = (const float*)d_in[5];
  const float* wk   = (const float*)d_in[6];
  const float* wv   = (const float*)d_in[7];
  const float* wg   = (const float*)d_in[8];
  const float* bg   = (const float*)d_in[9];
  const float* wo   = (const float*)d_in[10];
  const float* bo   = (const float*)d_in[11];
  float* out = (float*)d_out;

  char* ws = (char*)d_ws;
  unsigned short* qf  = (unsigned short*)(ws);                 // 16.7 MB frag-layout q
  unsigned short* kfb = (unsigned short*)(ws + 16777216L);     // 16.7 MB frag-layout k
  unsigned short* vt  = (unsigned short*)(ws + 33554432L);     // 16.7 MB swizzled V^T
  unsigned short* gg  = (unsigned short*)(ws + 50331648L);     // 16.7 MB gate bf16
  float* o   = (float*)(ws + 67108864L);                       // 33.5 MB gated o fp32
  float* b2d = (float*)(ws + 100663296L);                      // 1 MB pair bias
  unsigned short* pk = (unsigned short*)(ws + 101711872L);     // 320 KB packed weights

  k_prep<<<5, 256, 0, stream>>>(wq, wk, wv, wg, wo, pk);
  k_proj<<<512, 512, 0, stream>>>(act, ln_g, ln_b, w2d, pk, bg,
                                  qf, kfb, vt, gg, b2d);
  k_attn<<<1024, 256, 0, stream>>>(qf, kfb, vt, gg, b2d, mask, o);
  k_out<<<512, 512, 0, stream>>>(o, pk + 4*32768, bo, out);
}

// Round 5
// 108.312 us; speedup vs baseline: 4.6436x; 1.1780x over previous
//
#include <hip/hip_runtime.h>

#define QK_SCALE 0.17677669529663689f  // 1/sqrt(32)

typedef float f4 __attribute__((ext_vector_type(4)));
typedef short bf16x8 __attribute__((ext_vector_type(8)));
typedef float f32x4 __attribute__((ext_vector_type(4)));
typedef unsigned short us4 __attribute__((ext_vector_type(4)));

__device__ __forceinline__ unsigned short f2bf(float x){
  unsigned int u = __float_as_uint(x);
  u += 0x7fffu + ((u >> 16) & 1u);
  return (unsigned short)(u >> 16);
}
__device__ __forceinline__ float bf2f(unsigned short h){
  return __uint_as_float(((unsigned int)h) << 16);
}
__device__ __forceinline__ f32x4 mfma16(bf16x8 a, bf16x8 b, f32x4 c){
  return __builtin_amdgcn_mfma_f32_16x16x32_bf16(a, b, c, 0, 0, 0);
}
__device__ __forceinline__ void gload_lds16(const void* g, void* s){
  __builtin_amdgcn_global_load_lds(
      (const __attribute__((address_space(1))) unsigned int*)g,
      (__attribute__((address_space(3))) unsigned int*)s, 16, 0, 0);
}

// ---------------- Kernel 0: pack weights into MFMA B-fragment order ----------------
// layout per matrix (K=128, N=128): [nt(8)][kt(4)][hl(2)][lane(64)][e(8)] bf16
// value = W[kt*32 + (lane>>4)*8 + e][nt*16 + (lane&15)]  (wq pre-scaled)
__global__ __launch_bounds__(256)
void k_prep(const float* __restrict__ wq, const float* __restrict__ wk,
            const float* __restrict__ wv, const float* __restrict__ wg,
            const float* __restrict__ wo, unsigned short* __restrict__ pk)
{
  const int m = blockIdx.x;
  const float* W = (m==0)? wq : (m==1)? wk : (m==2)? wv : (m==3)? wg : wo;
  const float scale = (m==0)? QK_SCALE : 1.0f;
  unsigned short* dst = pk + (long)m * 32768;
  for (int ent = threadIdx.x; ent < 2048; ent += 256){
    const int l = ent & 63, ktn = ent >> 6;
    const int kt = ktn & 3, nt = ktn >> 2;
    unsigned short* ph = dst + ((nt*4 + kt)*2 + 0)*512 + l*8;
    unsigned short* pl = dst + ((nt*4 + kt)*2 + 1)*512 + l*8;
    #pragma unroll
    for (int e = 0; e < 8; ++e){
      const int row = kt*32 + (l>>4)*8 + e;
      const int col = nt*16 + (l&15);
      float v = W[row*128 + col] * scale;
      unsigned short hh = f2bf(v);
      ph[e] = hh;
      pl[e] = f2bf(v - bf2f(hh));
    }
  }
}

// ---------------- Kernel 1: LN + q/k/v/g projections + pair bias ----------------
// Direct global->reg loads in frag positions, LN via shuffles; one barrier.
__global__ __launch_bounds__(512, 4)
void k_proj(const float* __restrict__ act, const float* __restrict__ ln_g,
            const float* __restrict__ ln_b, const float* __restrict__ w2d,
            const unsigned short* __restrict__ pk, const float* __restrict__ bg,
            unsigned short* __restrict__ qf, unsigned short* __restrict__ kf,
            unsigned short* __restrict__ vt, unsigned short* __restrict__ gg,
            float* __restrict__ b2d)
{
  __shared__ unsigned short afr[8*4*2*512];  // 64 KB A-fragments hi/lo
  __shared__ unsigned short sc[4*640];       // 5 KB per-wave C->frag bounce (waves 0-3)
  const int t = threadIdx.x, w = t>>6, l = t&63, g16 = l>>4, c = l&15;
  const long p0 = (long)blockIdx.x * 128;
  const int bi = (int)(p0 >> 8);
  const int qb0 = (int)(p0 & 255);
  const int row = w*16 + c;

  // ---- load the lane's 32 act values (frag positions), LN, build afr + pair bias
  {
    const float* ap = act + (p0 + row)*128;
    f4 xv[4][2];
    #pragma unroll
    for (int kt = 0; kt < 4; ++kt){
      xv[kt][0] = *(const f4*)(ap + kt*32 + g16*8);
      xv[kt][1] = *(const f4*)(ap + kt*32 + g16*8 + 4);
    }
    float s = 0.f, s2 = 0.f;
    #pragma unroll
    for (int kt = 0; kt < 4; ++kt)
      #pragma unroll
      for (int u = 0; u < 2; ++u)
        #pragma unroll
        for (int e = 0; e < 4; ++e){
          float x = xv[kt][u][e]; s += x; s2 += x*x;
        }
    s += __shfl_xor(s,16); s2 += __shfl_xor(s2,16);
    s += __shfl_xor(s,32); s2 += __shfl_xor(s2,32);
    const float mu = s*(1.f/128.f);
    const float iv = rsqrtf(fmaxf(s2*(1.f/128.f)-mu*mu,0.f)+1e-5f);

    float pb0=0.f, pb1=0.f, pb2=0.f, pb3=0.f;
    #pragma unroll
    for (int kt = 0; kt < 4; ++kt){
      bf16x8 hv, lv;
      #pragma unroll
      for (int u = 0; u < 2; ++u){
        const int cb = kt*32 + g16*8 + u*4;
        f4 lg = *(const f4*)(ln_g + cb);
        f4 lb = *(const f4*)(ln_b + cb);
        #pragma unroll
        for (int e0 = 0; e0 < 4; ++e0){
          float vv = (xv[kt][u][e0]-mu)*iv*lg[e0] + lb[e0];
          f4 wp = *(const f4*)(w2d + (cb+e0)*4);
          pb0 += vv*wp[0]; pb1 += vv*wp[1]; pb2 += vv*wp[2]; pb3 += vv*wp[3];
          unsigned short hh = f2bf(vv);
          hv[u*4+e0] = (short)hh;
          lv[u*4+e0] = (short)f2bf(vv - bf2f(hh));
        }
      }
      *(bf16x8*)&afr[((w*4+kt)*2+0)*512 + l*8] = hv;
      *(bf16x8*)&afr[((w*4+kt)*2+1)*512 + l*8] = lv;
    }
    pb0 += __shfl_xor(pb0,16); pb1 += __shfl_xor(pb1,16);
    pb2 += __shfl_xor(pb2,16); pb3 += __shfl_xor(pb3,16);
    pb0 += __shfl_xor(pb0,32); pb1 += __shfl_xor(pb1,32);
    pb2 += __shfl_xor(pb2,32); pb3 += __shfl_xor(pb3,32);
    const float pbsel = (g16==0)? pb0 : (g16==1)? pb1 : (g16==2)? pb2 : pb3;
    b2d[g16*65536 + (int)p0 + row] = pbsel;
  }
  __syncthreads();

  // ---- GEMM over 32 N-tiles; wave owns 4 N-tiles (2 passes x 2); zero barriers
  #pragma unroll
  for (int pass = 0; pass < 2; ++pass){
    bf16x8 bh0[4], bl0[4], bh1[4], bl1[4];
    { const int ntg = w*4 + pass*2;
      #pragma unroll
      for (int kt = 0; kt < 4; ++kt){
        bh0[kt] = *(const bf16x8*)(pk + ((ntg*4+kt)*2+0)*512 + l*8);
        bl0[kt] = *(const bf16x8*)(pk + ((ntg*4+kt)*2+1)*512 + l*8);
        bh1[kt] = *(const bf16x8*)(pk + (((ntg+1)*4+kt)*2+0)*512 + l*8);
        bl1[kt] = *(const bf16x8*)(pk + (((ntg+1)*4+kt)*2+1)*512 + l*8);
      } }
    for (int rt = 0; rt < 8; ++rt){
      bf16x8 ah[4], al[4];
      #pragma unroll
      for (int kt = 0; kt < 4; ++kt){
        ah[kt] = *(const bf16x8*)&afr[((rt*4+kt)*2+0)*512 + l*8];
        al[kt] = *(const bf16x8*)&afr[((rt*4+kt)*2+1)*512 + l*8];
      }
      f32x4 a0 = {0.f,0.f,0.f,0.f}, a1 = {0.f,0.f,0.f,0.f};
      #pragma unroll
      for (int kt = 0; kt < 4; ++kt){
        a0 = mfma16(ah[kt], bh0[kt], a0);
        a1 = mfma16(ah[kt], bh1[kt], a1);
        a0 = mfma16(ah[kt], bl0[kt], a0);
        a1 = mfma16(ah[kt], bl1[kt], a1);
        a0 = mfma16(al[kt], bh0[kt], a0);
        a1 = mfma16(al[kt], bh1[kt], a1);
      }
      if (w < 4){           // q/k: C-tile -> row-major frag via wave-local bounce
        unsigned short* scw = sc + w*640;
        #pragma unroll
        for (int j = 0; j < 4; ++j){
          scw[(g16*4+j)*40 + c]      = f2bf(a0[j]);
          scw[(g16*4+j)*40 + 16 + c] = f2bf(a1[j]);
        }
        asm volatile("" ::: "memory");
        bf16x8 fr = *(const bf16x8*)&scw[c*40 + g16*8];
        const int head = (w&1)*2 + pass;
        unsigned short* dst = (w < 2) ? qf : kf;
        *(bf16x8*)&dst[(((long)bi*4+head)*16 + (qb0>>4) + rt)*512 + l*8] = fr;
        asm volatile("" ::: "memory");
      } else if (w < 6){    // v: transposed swizzled image
        const int ntv0 = (w-4)*4 + pass*2;
        const int kv = qb0 + rt*16 + g16*4;
        #pragma unroll
        for (int np = 0; np < 2; ++np){
          const int colg = (ntv0+np)*16 + c;
          const int head = colg >> 5, d = colg & 31;
          f32x4 aa = np ? a1 : a0;
          us4 v4;
          #pragma unroll
          for (int j = 0; j < 4; ++j) v4[j] = f2bf(aa[j]);
          const int vb = (d*512 + kv*2) ^ ((d&7)<<4);
          *(us4*)((char*)vt + ((long)bi*4+head)*16384 + vb) = v4;
        }
      } else {              // g: sigmoid(x@wg + bg), bf16 row-major
        const int colb = (w-6)*64 + pass*32;
        const int row0 = (int)p0 + rt*16 + g16*4;
        const float bg0 = bg[colb + c];
        const float bg1 = bg[colb + 16 + c];
        #pragma unroll
        for (int j = 0; j < 4; ++j){
          float g0 = 1.f/(1.f + __expf(-(a0[j] + bg0)));
          float g1 = 1.f/(1.f + __expf(-(a1[j] + bg1)));
          gg[(row0+j)*128 + colb + c]      = f2bf(g0);
          gg[(row0+j)*128 + colb + 16 + c] = f2bf(g1);
        }
      }
    }
  }
}

// ---------------- Kernel 2: attention (i,h)-block, 4 waves x 64 q-rows, gate fused --
// Writes o as bf16 row-major [pos][128].
__global__ __launch_bounds__(256, 3)
void k_attn(const unsigned short* __restrict__ qf, const unsigned short* __restrict__ kfg,
            const unsigned short* __restrict__ vt, const unsigned short* __restrict__ gg,
            const float* __restrict__ b2d, const float* __restrict__ mask,
            unsigned short* __restrict__ obf)
{
  __shared__ unsigned short k_s[16*512];   // 16 KB K fragments
  __shared__ unsigned short v_s[8192];     // 16 KB V^T swizzled image
  __shared__ unsigned short p_s[4*2112];   // 16.5 KB: per-wave 16x132 P half-tiles
  __shared__ float mb_s[256];
  const int t = threadIdx.x, w = t>>6, l = t&63, g16 = l>>4, c = l&15;
  const int bi = blockIdx.x >> 2, h = blockIdx.x & 3;
  const int base = (bi*4+h)*8192;

  #pragma unroll
  for (int cc = 0; cc < 8; ++cc){
    const int ch = w*8 + cc;
    if (ch < 16) gload_lds16(kfg + base + ch*512 + l*8, k_s + ch*512);
    else         gload_lds16(vt + base + (ch-16)*512 + l*8, v_s + (ch-16)*512);
  }
  mb_s[t] = 1e9f * (mask[bi*256 + t] - 1.0f);
  asm volatile("s_waitcnt vmcnt(0)" ::: "memory");
  __syncthreads();

  unsigned short* pw = p_s + w*2112;

  for (int im = 0; im < 4; ++im){
    const int q0 = w*64 + im*16;
    const bf16x8 qfr = *(const bf16x8*)(qf + base + (q0>>4)*512 + l*8);
    // ---- bias preload as C-init, then the QK^T MFMA burst
    f32x4 sa[16];
    const float* bq = b2d + h*65536 + (q0 + g16*4)*256;
    #pragma unroll
    for (int nt = 0; nt < 16; ++nt){
      const int kcol = nt*16 + c;
      const float mbv = mb_s[kcol];
      f32x4 ci;
      ci[0]=mbv+bq[kcol];     ci[1]=mbv+bq[256+kcol];
      ci[2]=mbv+bq[512+kcol]; ci[3]=mbv+bq[768+kcol];
      sa[nt] = ci;
    }
    #pragma unroll
    for (int nt = 0; nt < 16; ++nt)
      sa[nt] = mfma16(qfr, *(const bf16x8*)(k_s + nt*512 + l*8), sa[nt]);
    // ---- softmax (row r = g16*4+j lives across the 16 c-lanes)
    float mx0=-3e38f,mx1=-3e38f,mx2=-3e38f,mx3=-3e38f;
    #pragma unroll
    for (int nt = 0; nt < 16; ++nt){
      mx0 = fmaxf(mx0, sa[nt][0]); mx1 = fmaxf(mx1, sa[nt][1]);
      mx2 = fmaxf(mx2, sa[nt][2]); mx3 = fmaxf(mx3, sa[nt][3]);
    }
    #pragma unroll
    for (int d = 1; d < 16; d <<= 1){
      mx0 = fmaxf(mx0, __shfl_xor(mx0, d)); mx1 = fmaxf(mx1, __shfl_xor(mx1, d));
      mx2 = fmaxf(mx2, __shfl_xor(mx2, d)); mx3 = fmaxf(mx3, __shfl_xor(mx3, d));
    }
    float s0=0.f, s1=0.f, s2=0.f, s3=0.f;
    #pragma unroll
    for (int nt = 0; nt < 16; ++nt){
      float e0 = __expf(sa[nt][0]-mx0), e1 = __expf(sa[nt][1]-mx1);
      float e2 = __expf(sa[nt][2]-mx2), e3 = __expf(sa[nt][3]-mx3);
      s0 += e0; s1 += e1; s2 += e2; s3 += e3;
      sa[nt][0]=e0; sa[nt][1]=e1; sa[nt][2]=e2; sa[nt][3]=e3;
    }
    #pragma unroll
    for (int d = 1; d < 16; d <<= 1){
      s0 += __shfl_xor(s0, d); s1 += __shfl_xor(s1, d);
      s2 += __shfl_xor(s2, d); s3 += __shfl_xor(s3, d);
    }
    float invs[4] = {1.f/s0, 1.f/s1, 1.f/s2, 1.f/s3};
    // ---- PV in two 128-col phases reusing one per-wave P buffer
    f32x4 oa0 = {0.f,0.f,0.f,0.f}, oa1 = {0.f,0.f,0.f,0.f};
    #pragma unroll
    for (int ph = 0; ph < 2; ++ph){
      #pragma unroll
      for (int n8 = 0; n8 < 8; ++n8){
        const int nt = ph*8 + n8;
        const int cb = n8*16 + c;
        pw[(g16*4+0)*132 + cb] = f2bf(sa[nt][0]);
        pw[(g16*4+1)*132 + cb] = f2bf(sa[nt][1]);
        pw[(g16*4+2)*132 + cb] = f2bf(sa[nt][2]);
        pw[(g16*4+3)*132 + cb] = f2bf(sa[nt][3]);
      }
      asm volatile("s_waitcnt lgkmcnt(0)" ::: "memory");
      __builtin_amdgcn_sched_barrier(0);
      #pragma unroll
      for (int ktl = 0; ktl < 4; ++ktl){
        const int kt = ph*4 + ktl;
        bf16x8 pf = *(const bf16x8*)(pw + c*132 + ktl*32 + g16*8);
        const int vb0 = ((c*512      + kt*64 + g16*16) ^ ((c&7)<<4));
        const int vb1 = (((16+c)*512 + kt*64 + g16*16) ^ ((c&7)<<4));
        oa0 = mfma16(pf, *(const bf16x8*)((const char*)v_s + vb0), oa0);
        oa1 = mfma16(pf, *(const bf16x8*)((const char*)v_s + vb1), oa1);
      }
      asm volatile("" ::: "memory");
      __builtin_amdgcn_sched_barrier(0);
    }
    // ---- normalize, gate, store bf16
    const int row0 = bi*256 + q0 + g16*4;
    #pragma unroll
    for (int j = 0; j < 4; ++j){
      float gv0 = bf2f(gg[(row0+j)*128 + h*32 + c]);
      float gv1 = bf2f(gg[(row0+j)*128 + h*32 + 16 + c]);
      obf[(row0+j)*128 + h*32 + c]      = f2bf(oa0[j]*invs[j]*gv0);
      obf[(row0+j)*128 + h*32 + 16 + c] = f2bf(oa1[j]*invs[j]*gv1);
    }
  }
}

// ---------------- Kernel 3: out = o_gated(bf16) @ wo + bo ----------------
// A-frags = row-major 16B segments staged via global_load_lds; split-B in regs.
__global__ __launch_bounds__(512, 4)
void k_out(const unsigned short* __restrict__ obf, const unsigned short* __restrict__ pko,
           const float* __restrict__ bo, float* __restrict__ out)
{
  __shared__ unsigned short afr[32*512];   // 32 KB
  const int t = threadIdx.x, w = t>>6, l = t&63, g16 = l>>4, c = l&15;
  const long p0 = (long)blockIdx.x * 128;

  #pragma unroll
  for (int u = 0; u < 4; ++u){
    const int pr = w*4 + u;            // (rt,kt) pair 0..31
    const int rt = pr >> 2, kt = pr & 3;
    gload_lds16(obf + (p0 + rt*16 + c)*128 + kt*32 + g16*8, afr + pr*512);
  }
  asm volatile("s_waitcnt vmcnt(0)" ::: "memory");
  __syncthreads();

  bf16x8 bh[4], bl[4];
  #pragma unroll
  for (int kt = 0; kt < 4; ++kt){
    bh[kt] = *(const bf16x8*)(pko + ((w*4+kt)*2+0)*512 + l*8);
    bl[kt] = *(const bf16x8*)(pko + ((w*4+kt)*2+1)*512 + l*8);
  }
  const float bov = bo[w*16 + c];
  for (int rt = 0; rt < 8; ++rt){
    f32x4 a0 = {bov, bov, bov, bov};
    #pragma unroll
    for (int kt = 0; kt < 4; ++kt){
      bf16x8 af = *(const bf16x8*)&afr[(rt*4+kt)*512 + l*8];
      a0 = mfma16(af, bh[kt], a0);
      a0 = mfma16(af, bl[kt], a0);
    }
    const int row0 = (int)p0 + rt*16 + g16*4;
    #pragma unroll
    for (int j = 0; j < 4; ++j)
      out[(row0+j)*128 + w*16 + c] = a0[j];
  }
}

extern "C" void kernel_launch(void* const* d_in, const int* in_sizes, int n_in,
                              void* d_out, int out_size, void* d_ws, size_t ws_size,
                              hipStream_t stream) {
  const float* act  = (const float*)d_in[0];
  const float* mask = (const float*)d_in[1];
  const float* ln_g = (const float*)d_in[2];
  const float* ln_b = (const float*)d_in[3];
  const float* w2d  = (const float*)d_in[4];
  const float* wq   = (const float*)d_in[5];
  const float* wk   = (const float*)d_in[6];
  const float* wv   = (const float*)d_in[7];
  const float* wg   = (const float*)d_in[8];
  const float* bg   = (const float*)d_in[9];
  const float* wo   = (const float*)d_in[10];
  const float* bo   = (const float*)d_in[11];
  float* out = (float*)d_out;

  char* ws = (char*)d_ws;
  unsigned short* qf  = (unsigned short*)(ws);                 // 16.7 MB frag q
  unsigned short* kfb = (unsigned short*)(ws + 16777216L);     // 16.7 MB frag k
  unsigned short* vt  = (unsigned short*)(ws + 33554432L);     // 16.7 MB swizzled V^T
  unsigned short* gg  = (unsigned short*)(ws + 50331648L);     // 16.7 MB gate bf16
  unsigned short* obf = (unsigned short*)(ws + 67108864L);     // 16.7 MB gated o bf16
  float* b2d = (float*)(ws + 83886080L);                       // 1 MB pair bias
  unsigned short* pk = (unsigned short*)(ws + 84934656L);      // 320 KB packed weights

  k_prep<<<5, 256, 0, stream>>>(wq, wk, wv, wg, wo, pk);
  k_proj<<<512, 512, 0, stream>>>(act, ln_g, ln_b, w2d, pk, bg,
                                  qf, kfb, vt, gg, b2d);
  k_attn<<<1024, 256, 0, stream>>>(qf, kfb, vt, gg, b2d, mask, obf);
  k_out<<<512, 512, 0, stream>>>(obf, pk + 4*32768, bo, out);
}